// Round 3
// baseline (1664.088 us; speedup 1.0000x reference)
//
#include <hip/hip_runtime.h>
#include <math.h>

// Problem constants
constexpr int B_ = 4;
constexpr int N_ = 1024;
constexpr int C_ = 384;
constexpr int G_ = 2;
constexpr int K_ = 10;
constexpr int GD_ = 192;   // C_/G_
constexpr int NK_ = N_ * K_;           // 10240
constexpr int M2_ = B_ * G_ * N_ * K_; // 81920
constexpr float SCALE_ = 0.125f;       // 64^-0.5

// lexicographic (d, idx) compare == lax.top_k(-d) tie-break (lower idx wins)
__device__ __forceinline__ bool lless(double da, int ia, double db, int ib) {
  return (da < db) || (da == db && ia < ib);
}
__device__ __forceinline__ void lmin2(double& rd, int& ri, double ad, int ai,
                                      double bd, int bi) {
  bool t = lless(bd, bi, ad, ai);
  rd = t ? bd : ad; ri = t ? bi : ai;
}
__device__ __forceinline__ void lmax2(double& rd, int& ri, double ad, int ai,
                                      double bd, int bi) {
  bool t = lless(ad, ai, bd, bi);
  rd = t ? bd : ad; ri = t ? bi : ai;
}

// ---------------------------------------------------------------------------
// 1. fp64 squared norms of q_pos rows
__global__ void k_sqnorm64(const float* __restrict__ q_pos, double* __restrict__ s) {
  int i = blockIdx.x * blockDim.x + threadIdx.x;
  if (i >= B_ * N_) return;
  double x = q_pos[3 * i], y = q_pos[3 * i + 1], z = q_pos[3 * i + 2];
  s[i] = x * x + y * y + z * z;
}

// ---------------------------------------------------------------------------
// 2. KNN-10 in fp64 (selection-exact vs fp64 golden; gaps ~1e-2 >> 1e-14)
__global__ void k_knn10_64(const float* __restrict__ q_pos,
                           const double* __restrict__ s, int* __restrict__ idx10) {
  int i = blockIdx.x * blockDim.x + threadIdx.x;
  if (i >= B_ * N_) return;
  int b = i / N_;
  double px = q_pos[3 * i], py = q_pos[3 * i + 1], pz = q_pos[3 * i + 2];
  double sm = s[i];
  const float* bp = q_pos + b * N_ * 3;
  const double* bs = s + b * N_;
  double d10[K_]; int i10[K_];
  #pragma unroll
  for (int j = 0; j < K_; j++) { d10[j] = INFINITY; i10[j] = 0x7fffffff; }
  for (int n = 0; n < N_; n++) {
    double dot = px * (double)bp[3 * n] + py * (double)bp[3 * n + 1] +
                 pz * (double)bp[3 * n + 2];
    double d = (sm - 2.0 * dot) + bs[n];
    if (lless(d, n, d10[K_ - 1], i10[K_ - 1])) {
      int j = K_ - 1;
      while (j > 0 && lless(d, n, d10[j - 1], i10[j - 1])) {
        d10[j] = d10[j - 1]; i10[j] = i10[j - 1]; j--;
      }
      d10[j] = d; i10[j] = n;
    }
  }
  for (int j = 0; j < K_; j++) idx10[i * K_ + j] = i10[j];
}

// ---------------------------------------------------------------------------
// 3. fp32 GEMM: out[M x 384] = A @ W (+bias). Thread-per-column, TM rows/block.
template <int TM>
__global__ __launch_bounds__(384) void k_gemm384(const float* __restrict__ A,
                                                 const float* __restrict__ W,
                                                 const float* __restrict__ bias,
                                                 float* __restrict__ out, int M) {
  __shared__ float Al[TM][C_];
  int c = threadIdx.x;
  int r0 = blockIdx.x * TM;
  #pragma unroll
  for (int r = 0; r < TM; r++) Al[r][c] = A[(r0 + r) * C_ + c];
  __syncthreads();
  float acc[TM];
  #pragma unroll
  for (int r = 0; r < TM; r++) acc[r] = 0.f;
  #pragma unroll 4
  for (int j = 0; j < C_; j++) {
    float w = W[j * C_ + c];
    #pragma unroll
    for (int r = 0; r < TM; r++) acc[r] = fmaf(Al[r][j], w, acc[r]);
  }
  float bv = bias ? bias[c] : 0.f;
  #pragma unroll
  for (int r = 0; r < TM; r++) out[(r0 + r) * C_ + c] = acc[r] + bv;
}

// ---------------------------------------------------------------------------
// 4. Fused weight products (fp64):
//    M1[g][k][c] = sum_d Wvoff[k][g*GD+d] * W1[d][c]
//    M2[g][k][c] = sum_d Wq  [k][g*GD+d] * W1[GD+d][c]
__global__ __launch_bounds__(384) void k_prepM(const float* __restrict__ Wvoff,
                                               const float* __restrict__ Wq,
                                               const float* __restrict__ W1,
                                               double* __restrict__ M1,
                                               double* __restrict__ M2) {
  int g = blockIdx.x / C_;
  int k = blockIdx.x % C_;
  int c = threadIdx.x;
  const float* wv = Wvoff + k * C_ + g * GD_;
  const float* wq = Wq + k * C_ + g * GD_;
  double a1 = 0.0, a2 = 0.0;
  for (int d = 0; d < GD_; d++) {
    a1 += (double)wv[d] * (double)W1[d * C_ + c];
    a2 += (double)wq[d] * (double)W1[(GD_ + d) * C_ + c];
  }
  M1[(g * C_ + k) * C_ + c] = a1;
  M2[(g * C_ + k) * C_ + c] = a2;
}

// ---------------------------------------------------------------------------
// 5. Y1[b*N+r][g][c] = q[r] @ M1[g],  Y2 = q @ M2[g]   (fp64 accumulate)
template <int TM>
__global__ __launch_bounds__(384) void k_Y(const float* __restrict__ q,
                                           const double* __restrict__ M1,
                                           const double* __restrict__ M2,
                                           double* __restrict__ Y1,
                                           double* __restrict__ Y2) {
  __shared__ float Al[TM][C_];
  int c = threadIdx.x;
  int g = blockIdx.y;
  int r0 = blockIdx.x * TM;
  #pragma unroll
  for (int r = 0; r < TM; r++) Al[r][c] = q[(r0 + r) * C_ + c];
  __syncthreads();
  double a1[TM], a2[TM];
  #pragma unroll
  for (int r = 0; r < TM; r++) { a1[r] = 0.0; a2[r] = 0.0; }
  const double* m1 = M1 + (size_t)(g * C_) * C_ + c;
  const double* m2 = M2 + (size_t)(g * C_) * C_ + c;
  for (int k = 0; k < C_; k++) {
    double v1 = m1[(size_t)k * C_];
    double v2 = m2[(size_t)k * C_];
    #pragma unroll
    for (int r = 0; r < TM; r++) {
      double av = (double)Al[r][k];
      a1[r] += av * v1;
      a2[r] += av * v2;
    }
  }
  #pragma unroll
  for (int r = 0; r < TM; r++) {
    Y1[((size_t)(r0 + r) * G_ + g) * C_ + c] = a1[r];
    Y2[((size_t)(r0 + r) * G_ + g) * C_ + c] = a2[r];
  }
}

// ---------------------------------------------------------------------------
// 6. Per-row fp64: h = Y1[gathered] + Y2 + b1 -> LN -> gelu -> @W2 -> tanh
//    -> shift64 = q_pos[gathered] + offset.  One wave per row.
__global__ __launch_bounds__(256) void k_mlp64(const double* __restrict__ Y1,
                                               const double* __restrict__ Y2,
                                               const int* __restrict__ idx10,
                                               const float* __restrict__ q_pos,
                                               const float* __restrict__ b1,
                                               const float* __restrict__ ln_g,
                                               const float* __restrict__ ln_b,
                                               const float* __restrict__ W2,
                                               double* __restrict__ shift64) {
  int w_ = threadIdx.x >> 6, l = threadIdx.x & 63;
  int row = blockIdx.x * 4 + w_;
  int k = row % K_; int t = row / K_;
  int n = t % N_; t /= N_;
  int g = t % G_; int b = t / G_;
  int j = idx10[(b * N_ + n) * K_ + k];
  const double* y1 = Y1 + ((size_t)(b * N_ + j) * G_ + g) * C_;
  const double* y2 = Y2 + ((size_t)(b * N_ + n) * G_ + g) * C_;
  double x[6];
  #pragma unroll
  for (int jj = 0; jj < 6; jj++) {
    int col = l + 64 * jj;
    x[jj] = y1[col] + y2[col] + (double)b1[col];
  }
  double sum = ((((x[0] + x[1]) + x[2]) + x[3]) + x[4]) + x[5];
  #pragma unroll
  for (int off = 1; off < 64; off <<= 1) sum += __shfl_xor(sum, off);
  double mu = sum / 384.0;
  double sq = 0.0;
  #pragma unroll
  for (int jj = 0; jj < 6; jj++) { double d = x[jj] - mu; sq += d * d; }
  #pragma unroll
  for (int off = 1; off < 64; off <<= 1) sq += __shfl_xor(sq, off);
  double var = sq / 384.0;
  double rstd = 1.0 / sqrt(var + 1e-5);
  double ge[6];
  #pragma unroll
  for (int jj = 0; jj < 6; jj++) {
    int col = l + 64 * jj;
    double nv = (x[jj] - mu) * rstd * (double)ln_g[col] + (double)ln_b[col];
    ge[jj] = 0.5 * nv * (1.0 + erf(nv * 0.70710678118654752440));
  }
  double o3[3];
  #pragma unroll
  for (int o = 0; o < 3; o++) {
    double p = 0.0;
    #pragma unroll
    for (int jj = 0; jj < 6; jj++) {
      int col = l + 64 * jj;
      p += ge[jj] * (double)W2[col * 3 + o];
    }
    #pragma unroll
    for (int off = 1; off < 64; off <<= 1) p += __shfl_xor(p, off);
    o3[o] = tanh(p);
  }
  if (l == 0) {
    int gi = b * N_ + j;
    shift64[(size_t)row * 3 + 0] = (double)q_pos[gi * 3 + 0] + o3[0];
    shift64[(size_t)row * 3 + 1] = (double)q_pos[gi * 3 + 1] + o3[1];
    shift64[(size_t)row * 3 + 2] = (double)q_pos[gi * 3 + 2] + o3[2];
  }
}

// ---------------------------------------------------------------------------
// 7. fp64 top-3 + inverse-distance interp. One wave per (b,g,m).
__global__ __launch_bounds__(256) void k_interp64(const double* __restrict__ shift64,
                                                  const float* __restrict__ q_pos,
                                                  const double* __restrict__ s64,
                                                  const float* __restrict__ q,
                                                  float* __restrict__ interp) {
  int wid = (blockIdx.x * blockDim.x + threadIdx.x) >> 6;
  int lane = threadIdx.x & 63;
  int m = wid % NK_; int t = wid / NK_;
  int g = t % G_; int b = t / G_;
  double px = shift64[(size_t)wid * 3], py = shift64[(size_t)wid * 3 + 1],
         pz = shift64[(size_t)wid * 3 + 2];
  double sp = px * px + py * py + pz * pz;
  const float* bp = q_pos + b * N_ * 3;
  const double* bs = s64 + b * N_;
  double d0 = INFINITY, d1 = INFINITY, d2 = INFINITY;
  int i0 = 0x7fffffff, i1 = 0x7fffffff, i2 = 0x7fffffff;
  for (int n = lane; n < N_; n += 64) {
    double dot = px * (double)bp[3 * n] + py * (double)bp[3 * n + 1] +
                 pz * (double)bp[3 * n + 2];
    double d = (sp - 2.0 * dot) + bs[n];
    // branchless sorted-triple insert (register-only)
    bool c0 = lless(d, n, d0, i0);
    bool c1 = lless(d, n, d1, i1);
    bool c2 = lless(d, n, d2, i2);
    double nd2 = c2 ? (c1 ? d1 : d) : d2; int ni2 = c2 ? (c1 ? i1 : n) : i2;
    double nd1 = c1 ? (c0 ? d0 : d) : d1; int ni1 = c1 ? (c0 ? i0 : n) : i1;
    double nd0 = c0 ? d : d0;             int ni0 = c0 ? n : i0;
    d0 = nd0; d1 = nd1; d2 = nd2; i0 = ni0; i1 = ni1; i2 = ni2;
  }
  // butterfly merge of sorted triples: m0=min(a0,b0); m1=min(a1,b1,max(a0,b0));
  // m2=min(a2,b2,max(a1,b0),max(a0,b1))
  #pragma unroll
  for (int off = 1; off < 64; off <<= 1) {
    double e0 = __shfl_xor(d0, off), e1 = __shfl_xor(d1, off), e2 = __shfl_xor(d2, off);
    int j0 = __shfl_xor(i0, off), j1 = __shfl_xor(i1, off), j2 = __shfl_xor(i2, off);
    double mnd, mxd, p1d, q1d, q2d, q3d, q4d, t1d, t2d;
    int mni, mxi, p1i, q1i, q2i, q3i, q4i, t1i, t2i;
    lmin2(mnd, mni, d0, i0, e0, j0);
    lmax2(mxd, mxi, d0, i0, e0, j0);
    lmin2(p1d, p1i, d1, i1, e1, j1);
    lmin2(t1d, t1i, p1d, p1i, mxd, mxi);
    lmax2(q1d, q1i, d1, i1, e0, j0);
    lmax2(q2d, q2i, d0, i0, e1, j1);
    lmin2(q3d, q3i, q1d, q1i, q2d, q2i);
    lmin2(q4d, q4i, d2, i2, e2, j2);
    lmin2(t2d, t2i, q3d, q3i, q4d, q4i);
    d0 = mnd; i0 = mni; d1 = t1d; i1 = t1i; d2 = t2d; i2 = t2i;
  }
  double r0 = 1.0 / (d0 + 1e-8);
  double r1 = 1.0 / (d1 + 1e-8);
  double r2 = 1.0 / (d2 + 1e-8);
  double rs = (r0 + r1) + r2;
  double w0 = r0 / rs, w1 = r1 / rs, w2 = r2 / rs;
  const float* qb = q + (size_t)b * N_ * C_ + g * GD_;
  const float* p0 = qb + (size_t)i0 * C_;
  const float* p1 = qb + (size_t)i1 * C_;
  const float* p2 = qb + (size_t)i2 * C_;
  int n_ = m / K_, k_ = m % K_;
  float* op = interp + (((size_t)(b * N_ + n_) * K_ + k_) * C_) + g * GD_;
  for (int cc = lane; cc < GD_; cc += 64) {
    op[cc] = (float)((w0 * (double)p0[cc] + w1 * (double)p1[cc]) + w2 * (double)p2[cc]);
  }
}

// ---------------------------------------------------------------------------
// 8. Fused kk/vv projection + softmax attention. Block per (b,n), 384 threads.
__global__ __launch_bounds__(384) void k_attn(const float* __restrict__ interp,
                                              const float* __restrict__ qp,
                                              const float* __restrict__ Wk,
                                              const float* __restrict__ Wv,
                                              float* __restrict__ attn_out) {
  __shared__ float Al[K_][C_];
  __shared__ float kkl[K_][C_];
  __shared__ float vvl[K_][C_];
  int c = threadIdx.x;
  int bn = blockIdx.x;
  #pragma unroll
  for (int k = 0; k < K_; k++) Al[k][c] = interp[((size_t)bn * K_ + k) * C_ + c];
  __syncthreads();
  float ak[K_], av[K_];
  #pragma unroll
  for (int k = 0; k < K_; k++) { ak[k] = 0.f; av[k] = 0.f; }
  #pragma unroll 2
  for (int j = 0; j < C_; j++) {
    float wk = Wk[j * C_ + c];
    float wv = Wv[j * C_ + c];
    #pragma unroll
    for (int k = 0; k < K_; k++) {
      ak[k] = fmaf(Al[k][j], wk, ak[k]);
      av[k] = fmaf(Al[k][j], wv, av[k]);
    }
  }
  #pragma unroll
  for (int k = 0; k < K_; k++) { kkl[k][c] = ak[k]; vvl[k][c] = av[k]; }
  __syncthreads();
  float qd = qp[bn * C_ + c];
  float logit[K_];
  #pragma unroll
  for (int k = 0; k < K_; k++) {
    float p = qd * kkl[k][c];
    #pragma unroll
    for (int off = 1; off < 64; off <<= 1) p += __shfl_xor(p, off);
    logit[k] = p * SCALE_;
  }
  float mx = logit[0];
  #pragma unroll
  for (int k = 1; k < K_; k++) mx = fmaxf(mx, logit[k]);
  float e[K_], se = 0.f;
  #pragma unroll
  for (int k = 0; k < K_; k++) { e[k] = expf(logit[k] - mx); se += e[k]; }
  float od = 0.f;
  #pragma unroll
  for (int k = 0; k < K_; k++) od = fmaf(e[k] / se, vvl[k][c], od);
  attn_out[(size_t)bn * C_ + c] = od;
}

// ---------------------------------------------------------------------------
extern "C" void kernel_launch(void* const* d_in, const int* in_sizes, int n_in,
                              void* d_out, int out_size, void* d_ws, size_t ws_size,
                              hipStream_t stream) {
  const float* q     = (const float*)d_in[0];
  const float* q_pos = (const float*)d_in[1];
  const float* Wq    = (const float*)d_in[2];
  const float* Wk    = (const float*)d_in[3];
  const float* Wv    = (const float*)d_in[4];
  const float* Wvoff = (const float*)d_in[5];
  const float* W1    = (const float*)d_in[6];
  const float* b1    = (const float*)d_in[7];
  const float* ln_g  = (const float*)d_in[8];
  const float* ln_b  = (const float*)d_in[9];
  const float* W2    = (const float*)d_in[10];
  const float* Wproj = (const float*)d_in[11];
  const float* bproj = (const float*)d_in[12];
  float* out = (float*)d_out;

  char* ws = (char*)d_ws;
  double* s64     = (double*)ws; ws += (size_t)B_ * N_ * 8;               // 32 KB
  int*    idx10   = (int*)ws;    ws += (size_t)B_ * N_ * K_ * 4;          // 160 KB
  float*  qp32    = (float*)ws;  ws += (size_t)B_ * N_ * C_ * 4;          // 6.3 MB
  double* M1      = (double*)ws; ws += (size_t)G_ * C_ * C_ * 8;          // 2.4 MB
  double* M2      = (double*)ws; ws += (size_t)G_ * C_ * C_ * 8;          // 2.4 MB
  double* Y1      = (double*)ws; ws += (size_t)B_ * N_ * G_ * C_ * 8;     // 25.2 MB
  double* Y2      = (double*)ws; ws += (size_t)B_ * N_ * G_ * C_ * 8;     // 25.2 MB
  double* shift64 = (double*)ws; ws += (size_t)M2_ * 3 * 8;               // 2 MB
  float*  interp  = (float*)ws;  ws += (size_t)B_ * N_ * K_ * C_ * 4;     // 63 MB
  float*  attn_out= (float*)ws;  ws += (size_t)B_ * N_ * C_ * 4;          // 6.3 MB

  k_sqnorm64<<<(B_ * N_ + 255) / 256, 256, 0, stream>>>(q_pos, s64);
  k_knn10_64<<<(B_ * N_ + 255) / 256, 256, 0, stream>>>(q_pos, s64, idx10);
  k_gemm384<16><<<B_ * N_ / 16, 384, 0, stream>>>(q, Wq, nullptr, qp32, B_ * N_);
  k_prepM<<<G_ * C_, 384, 0, stream>>>(Wvoff, Wq, W1, M1, M2);
  k_Y<16><<<dim3(B_ * N_ / 16, G_), 384, 0, stream>>>(q, M1, M2, Y1, Y2);
  k_mlp64<<<M2_ / 4, 256, 0, stream>>>(Y1, Y2, idx10, q_pos, b1, ln_g, ln_b, W2,
                                       shift64);
  k_interp64<<<M2_ / 4, 256, 0, stream>>>(shift64, q_pos, s64, q, interp);
  k_attn<<<B_ * N_, 384, 0, stream>>>(interp, qp32, Wk, Wv, attn_out);
  k_gemm384<16><<<B_ * N_ / 16, 384, 0, stream>>>(attn_out, Wproj, bproj, out, B_ * N_);
}

// Round 5
// 935.872 us; speedup vs baseline: 1.7781x; 1.7781x over previous
//
#include <hip/hip_runtime.h>
#include <math.h>

// Problem constants
constexpr int B_ = 4;
constexpr int N_ = 1024;
constexpr int C_ = 384;
constexpr int G_ = 2;
constexpr int K_ = 10;
constexpr int GD_ = 192;   // C_/G_
constexpr int NK_ = N_ * K_;           // 10240
constexpr int M2_ = B_ * G_ * N_ * K_; // 81920
constexpr float SCALE_ = 0.125f;       // 64^-0.5

// lexicographic (d, idx) compare == lax.top_k(-d) tie-break (lower idx wins)
__device__ __forceinline__ bool lless(double da, int ia, double db, int ib) {
  return (da < db) || (da == db && ia < ib);
}
__device__ __forceinline__ void lmin2(double& rd, int& ri, double ad, int ai,
                                      double bd, int bi) {
  bool t = lless(bd, bi, ad, ai);
  rd = t ? bd : ad; ri = t ? bi : ai;
}
__device__ __forceinline__ void lmax2(double& rd, int& ri, double ad, int ai,
                                      double bd, int bi) {
  bool t = lless(ad, ai, bd, bi);
  rd = t ? bd : ad; ri = t ? bi : ai;
}

// ---------------------------------------------------------------------------
// 1. fp64 squared norms of q_pos rows
__global__ void k_sqnorm64(const float* __restrict__ q_pos, double* __restrict__ s) {
  int i = blockIdx.x * blockDim.x + threadIdx.x;
  if (i >= B_ * N_) return;
  double x = q_pos[3 * i], y = q_pos[3 * i + 1], z = q_pos[3 * i + 2];
  s[i] = x * x + y * y + z * z;
}

// ---------------------------------------------------------------------------
// 2. KNN-10, wave-parallel: one 64-lane wave per query. Per-lane sorted top-10
//    over 16 strided candidates (branchless insertion network, fully unrolled),
//    then 6-step butterfly merge: C[r] = min(A[r],B[r], min_j max(A[j-1],B[r-j]))
__global__ __launch_bounds__(256) void k_knn10_w(const float* __restrict__ q_pos,
                                                 const double* __restrict__ s,
                                                 int* __restrict__ idx10) {
  int wid = (blockIdx.x * blockDim.x + threadIdx.x) >> 6;
  int lane = threadIdx.x & 63;
  if (wid >= B_ * N_) return;
  int b = wid / N_;
  double px = q_pos[3 * wid], py = q_pos[3 * wid + 1], pz = q_pos[3 * wid + 2];
  double sm = s[wid];
  const float* bp = q_pos + b * N_ * 3;
  const double* bs = s + b * N_;
  double d[K_]; int ix[K_];
  #pragma unroll
  for (int j = 0; j < K_; j++) { d[j] = INFINITY; ix[j] = 0x7fffffff; }
  for (int n0 = 0; n0 < N_; n0 += 64) {
    int n = n0 + lane;
    double dot = px * (double)bp[3 * n] + py * (double)bp[3 * n + 1] +
                 pz * (double)bp[3 * n + 2];
    double v = (sm - 2.0 * dot) + bs[n];
    bool c[K_];
    #pragma unroll
    for (int j = 0; j < K_; j++) c[j] = lless(v, n, d[j], ix[j]);
    #pragma unroll
    for (int j = K_ - 1; j >= 1; j--) {
      d[j]  = c[j] ? (c[j - 1] ? d[j - 1] : v) : d[j];
      ix[j] = c[j] ? (c[j - 1] ? ix[j - 1] : n) : ix[j];
    }
    d[0]  = c[0] ? v : d[0];
    ix[0] = c[0] ? n : ix[0];
  }
  #pragma unroll
  for (int off = 1; off < 64; off <<= 1) {
    double bd[K_]; int bi[K_];
    #pragma unroll
    for (int j = 0; j < K_; j++) {
      bd[j] = __shfl_xor(d[j], off);
      bi[j] = __shfl_xor(ix[j], off);
    }
    double md[K_]; int mi[K_];
    #pragma unroll
    for (int r = 0; r < K_; r++) {
      double m; int mj;
      lmin2(m, mj, d[r], ix[r], bd[r], bi[r]);
      #pragma unroll
      for (int j = 1; j <= r; j++) {
        double t; int ti;
        lmax2(t, ti, d[j - 1], ix[j - 1], bd[r - j], bi[r - j]);
        lmin2(m, mj, m, mj, t, ti);
      }
      md[r] = m; mi[r] = mj;
    }
    #pragma unroll
    for (int j = 0; j < K_; j++) { d[j] = md[j]; ix[j] = mi[j]; }
  }
  if (lane == 0) {
    #pragma unroll
    for (int j = 0; j < K_; j++) idx10[wid * K_ + j] = ix[j];
  }
}

// ---------------------------------------------------------------------------
// 3. fp32 GEMM, scalar-A: out[M x 384] = A @ W (+bias). Thread-per-column,
//    TM rows/block; A read via uniform addresses -> s_load, no LDS.
template <int TM>
__global__ __launch_bounds__(384) void k_gemmSA(const float* __restrict__ A,
                                                const float* __restrict__ W,
                                                const float* __restrict__ bias,
                                                float* __restrict__ out, int M) {
  int c = threadIdx.x;
  int r0 = blockIdx.x * TM;
  float acc[TM];
  #pragma unroll
  for (int r = 0; r < TM; r++) acc[r] = 0.f;
  #pragma unroll 4
  for (int j = 0; j < C_; j++) {
    float w = W[j * C_ + c];
    #pragma unroll
    for (int r = 0; r < TM; r++) acc[r] = fmaf(A[(r0 + r) * C_ + j], w, acc[r]);
  }
  float bv = bias ? bias[c] : 0.f;
  #pragma unroll
  for (int r = 0; r < TM; r++) out[(r0 + r) * C_ + c] = acc[r] + bv;
}

// ---------------------------------------------------------------------------
// 4. Fused weight products (fp64):
//    M1[g][k][c] = sum_d Wvoff[k][g*GD+d] * W1[d][c]
//    M2[g][k][c] = sum_d Wq  [k][g*GD+d] * W1[GD+d][c]
__global__ __launch_bounds__(384) void k_prepM(const float* __restrict__ Wvoff,
                                               const float* __restrict__ Wq,
                                               const float* __restrict__ W1,
                                               double* __restrict__ M1,
                                               double* __restrict__ M2) {
  int g = blockIdx.x / C_;
  int k = blockIdx.x % C_;
  int c = threadIdx.x;
  const float* wv = Wvoff + k * C_ + g * GD_;
  const float* wq = Wq + k * C_ + g * GD_;
  double a1 = 0.0, a2 = 0.0;
  for (int d = 0; d < GD_; d++) {
    a1 += (double)wv[d] * (double)W1[d * C_ + c];
    a2 += (double)wq[d] * (double)W1[(GD_ + d) * C_ + c];
  }
  M1[(g * C_ + k) * C_ + c] = a1;
  M2[(g * C_ + k) * C_ + c] = a2;
}

// ---------------------------------------------------------------------------
// 5. Y1 = q @ M1[g], Y2 = q @ M2[g]  (fp64 accumulate; scalar-A, no LDS)
template <int TM>
__global__ __launch_bounds__(384) void k_Y(const float* __restrict__ q,
                                           const double* __restrict__ M1,
                                           const double* __restrict__ M2,
                                           double* __restrict__ Y1,
                                           double* __restrict__ Y2) {
  int c = threadIdx.x;
  int g = blockIdx.y;
  int r0 = blockIdx.x * TM;
  double a1[TM], a2[TM];
  #pragma unroll
  for (int r = 0; r < TM; r++) { a1[r] = 0.0; a2[r] = 0.0; }
  const double* m1 = M1 + (size_t)(g * C_) * C_ + c;
  const double* m2 = M2 + (size_t)(g * C_) * C_ + c;
  for (int k = 0; k < C_; k++) {
    double v1 = m1[(size_t)k * C_];
    double v2 = m2[(size_t)k * C_];
    #pragma unroll
    for (int r = 0; r < TM; r++) {
      double av = (double)q[(r0 + r) * C_ + k];
      a1[r] += av * v1;
      a2[r] += av * v2;
    }
  }
  #pragma unroll
  for (int r = 0; r < TM; r++) {
    Y1[((size_t)(r0 + r) * G_ + g) * C_ + c] = a1[r];
    Y2[((size_t)(r0 + r) * G_ + g) * C_ + c] = a2[r];
  }
}

// ---------------------------------------------------------------------------
// 6. Per-row fp64: h = Y1[gathered] + Y2 + b1 -> LN -> gelu -> @W2 -> tanh
//    -> shift64 = q_pos[gathered] + offset.  One wave per row.
__global__ __launch_bounds__(256) void k_mlp64(const double* __restrict__ Y1,
                                               const double* __restrict__ Y2,
                                               const int* __restrict__ idx10,
                                               const float* __restrict__ q_pos,
                                               const float* __restrict__ b1,
                                               const float* __restrict__ ln_g,
                                               const float* __restrict__ ln_b,
                                               const float* __restrict__ W2,
                                               double* __restrict__ shift64) {
  int w_ = threadIdx.x >> 6, l = threadIdx.x & 63;
  int row = blockIdx.x * 4 + w_;
  int k = row % K_; int t = row / K_;
  int n = t % N_; t /= N_;
  int g = t % G_; int b = t / G_;
  int j = idx10[(b * N_ + n) * K_ + k];
  const double* y1 = Y1 + ((size_t)(b * N_ + j) * G_ + g) * C_;
  const double* y2 = Y2 + ((size_t)(b * N_ + n) * G_ + g) * C_;
  double x[6];
  #pragma unroll
  for (int jj = 0; jj < 6; jj++) {
    int col = l + 64 * jj;
    x[jj] = y1[col] + y2[col] + (double)b1[col];
  }
  double sum = ((((x[0] + x[1]) + x[2]) + x[3]) + x[4]) + x[5];
  #pragma unroll
  for (int off = 1; off < 64; off <<= 1) sum += __shfl_xor(sum, off);
  double mu = sum / 384.0;
  double sq = 0.0;
  #pragma unroll
  for (int jj = 0; jj < 6; jj++) { double dd = x[jj] - mu; sq += dd * dd; }
  #pragma unroll
  for (int off = 1; off < 64; off <<= 1) sq += __shfl_xor(sq, off);
  double var = sq / 384.0;
  double rstd = 1.0 / sqrt(var + 1e-5);
  double ge[6];
  #pragma unroll
  for (int jj = 0; jj < 6; jj++) {
    int col = l + 64 * jj;
    double nv = (x[jj] - mu) * rstd * (double)ln_g[col] + (double)ln_b[col];
    ge[jj] = 0.5 * nv * (1.0 + erf(nv * 0.70710678118654752440));
  }
  double o3[3];
  #pragma unroll
  for (int o = 0; o < 3; o++) {
    double p = 0.0;
    #pragma unroll
    for (int jj = 0; jj < 6; jj++) {
      int col = l + 64 * jj;
      p += ge[jj] * (double)W2[col * 3 + o];
    }
    #pragma unroll
    for (int off = 1; off < 64; off <<= 1) p += __shfl_xor(p, off);
    o3[o] = tanh(p);
  }
  if (l == 0) {
    int gi = b * N_ + j;
    shift64[(size_t)row * 3 + 0] = (double)q_pos[gi * 3 + 0] + o3[0];
    shift64[(size_t)row * 3 + 1] = (double)q_pos[gi * 3 + 1] + o3[1];
    shift64[(size_t)row * 3 + 2] = (double)q_pos[gi * 3 + 2] + o3[2];
  }
}

// ---------------------------------------------------------------------------
// 7. fp64 top-3 + inverse-distance interp. One wave per (b,g,m).
__global__ __launch_bounds__(256) void k_interp64(const double* __restrict__ shift64,
                                                  const float* __restrict__ q_pos,
                                                  const double* __restrict__ s64,
                                                  const float* __restrict__ q,
                                                  float* __restrict__ interp) {
  int wid = (blockIdx.x * blockDim.x + threadIdx.x) >> 6;
  int lane = threadIdx.x & 63;
  int m = wid % NK_; int t = wid / NK_;
  int g = t % G_; int b = t / G_;
  double px = shift64[(size_t)wid * 3], py = shift64[(size_t)wid * 3 + 1],
         pz = shift64[(size_t)wid * 3 + 2];
  double sp = px * px + py * py + pz * pz;
  const float* bp = q_pos + b * N_ * 3;
  const double* bs = s64 + b * N_;
  double d0 = INFINITY, d1 = INFINITY, d2 = INFINITY;
  int i0 = 0x7fffffff, i1 = 0x7fffffff, i2 = 0x7fffffff;
  for (int n = lane; n < N_; n += 64) {
    double dot = px * (double)bp[3 * n] + py * (double)bp[3 * n + 1] +
                 pz * (double)bp[3 * n + 2];
    double dd = (sp - 2.0 * dot) + bs[n];
    bool c0 = lless(dd, n, d0, i0);
    bool c1 = lless(dd, n, d1, i1);
    bool c2 = lless(dd, n, d2, i2);
    double nd2 = c2 ? (c1 ? d1 : dd) : d2; int ni2 = c2 ? (c1 ? i1 : n) : i2;
    double nd1 = c1 ? (c0 ? d0 : dd) : d1; int ni1 = c1 ? (c0 ? i0 : n) : i1;
    double nd0 = c0 ? dd : d0;             int ni0 = c0 ? n : i0;
    d0 = nd0; d1 = nd1; d2 = nd2; i0 = ni0; i1 = ni1; i2 = ni2;
  }
  #pragma unroll
  for (int off = 1; off < 64; off <<= 1) {
    double e0 = __shfl_xor(d0, off), e1 = __shfl_xor(d1, off), e2 = __shfl_xor(d2, off);
    int j0 = __shfl_xor(i0, off), j1 = __shfl_xor(i1, off), j2 = __shfl_xor(i2, off);
    double mnd, mxd, p1d, q1d, q2d, q3d, q4d, t1d, t2d;
    int mni, mxi, p1i, q1i, q2i, q3i, q4i, t1i, t2i;
    lmin2(mnd, mni, d0, i0, e0, j0);
    lmax2(mxd, mxi, d0, i0, e0, j0);
    lmin2(p1d, p1i, d1, i1, e1, j1);
    lmin2(t1d, t1i, p1d, p1i, mxd, mxi);
    lmax2(q1d, q1i, d1, i1, e0, j0);
    lmax2(q2d, q2i, d0, i0, e1, j1);
    lmin2(q3d, q3i, q1d, q1i, q2d, q2i);
    lmin2(q4d, q4i, d2, i2, e2, j2);
    lmin2(t2d, t2i, q3d, q3i, q4d, q4i);
    d0 = mnd; i0 = mni; d1 = t1d; i1 = t1i; d2 = t2d; i2 = t2i;
  }
  double r0 = 1.0 / (d0 + 1e-8);
  double r1 = 1.0 / (d1 + 1e-8);
  double r2 = 1.0 / (d2 + 1e-8);
  double rs = (r0 + r1) + r2;
  double w0 = r0 / rs, w1 = r1 / rs, w2 = r2 / rs;
  const float* qb = q + (size_t)b * N_ * C_ + g * GD_;
  const float* p0 = qb + (size_t)i0 * C_;
  const float* p1 = qb + (size_t)i1 * C_;
  const float* p2 = qb + (size_t)i2 * C_;
  int n_ = m / K_, k_ = m % K_;
  float* op = interp + (((size_t)(b * N_ + n_) * K_ + k_) * C_) + g * GD_;
  for (int cc = lane; cc < GD_; cc += 64) {
    op[cc] = (float)((w0 * (double)p0[cc] + w1 * (double)p1[cc]) + w2 * (double)p2[cc]);
  }
}

// ---------------------------------------------------------------------------
// 8a. Transpose Wk -> WkT (WkT[col][row] = Wk[row][col])
__global__ __launch_bounds__(256) void k_T(const float* __restrict__ Wk,
                                           float* __restrict__ WkT) {
  int i = blockIdx.x * blockDim.x + threadIdx.x;
  if (i >= C_ * C_) return;
  int r = i / C_, c = i % C_;
  WkT[c * C_ + r] = Wk[i];
}

// ---------------------------------------------------------------------------
// 8b. U[bn][h][c] = sum_d qp[bn, h*64+d] * Wk[c, h*64+d]  (via WkT, scalar-A qp)
template <int TM>
__global__ __launch_bounds__(384) void k_U(const float* __restrict__ qp,
                                           const float* __restrict__ WkT,
                                           float* __restrict__ U) {
  int c = threadIdx.x;
  int r0 = blockIdx.x * TM;
  for (int h = 0; h < 6; h++) {
    float acc[TM];
    #pragma unroll
    for (int r = 0; r < TM; r++) acc[r] = 0.f;
    #pragma unroll 4
    for (int dd = 0; dd < 64; dd++) {
      float w = WkT[(h * 64 + dd) * C_ + c];
      #pragma unroll
      for (int r = 0; r < TM; r++)
        acc[r] = fmaf(qp[(r0 + r) * C_ + h * 64 + dd], w, acc[r]);
    }
    #pragma unroll
    for (int r = 0; r < TM; r++) U[((size_t)(r0 + r) * 6 + h) * C_ + c] = acc[r];
  }
}

// ---------------------------------------------------------------------------
// 8c. Per (bn, h) wave: logits = interp·U, softmax, mix = attn·interp.
//     Writes mix IN PLACE over U (same row, read fully before write).
__global__ __launch_bounds__(256) void k_attn2(const float* __restrict__ interp,
                                               float* __restrict__ Umix) {
  int wid = blockIdx.x * 4 + (threadIdx.x >> 6);
  int lane = threadIdx.x & 63;
  int h = wid % 6, bn = wid / 6;
  float* urow = Umix + (size_t)wid * C_;
  float u[6];
  #pragma unroll
  for (int j = 0; j < 6; j++) u[j] = urow[lane + 64 * j];
  float logit[K_];
  #pragma unroll
  for (int k = 0; k < K_; k++) {
    const float* ip = interp + ((size_t)bn * K_ + k) * C_;
    float p = 0.f;
    #pragma unroll
    for (int j = 0; j < 6; j++) p = fmaf(ip[lane + 64 * j], u[j], p);
    #pragma unroll
    for (int off = 1; off < 64; off <<= 1) p += __shfl_xor(p, off);
    logit[k] = p * SCALE_;
  }
  float mx = logit[0];
  #pragma unroll
  for (int k = 1; k < K_; k++) mx = fmaxf(mx, logit[k]);
  float e[K_], se = 0.f;
  #pragma unroll
  for (int k = 0; k < K_; k++) { e[k] = expf(logit[k] - mx); se += e[k]; }
  float inv = 1.0f / se;
  #pragma unroll
  for (int k = 0; k < K_; k++) e[k] *= inv;
  #pragma unroll
  for (int j = 0; j < 6; j++) {
    float mv = 0.f;
    #pragma unroll
    for (int k = 0; k < K_; k++)
      mv = fmaf(e[k], interp[((size_t)bn * K_ + k) * C_ + lane + 64 * j], mv);
    urow[lane + 64 * j] = mv;
  }
  (void)h;
}

// ---------------------------------------------------------------------------
// 8d. attn_out[bn, c] = mix[bn, c/64, :] @ Wv[:, c]  (scalar-A mix via
//     readfirstlane'd head index -> s_load)
template <int TM>
__global__ __launch_bounds__(384) void k_out(const float* __restrict__ mix,
                                             const float* __restrict__ Wv,
                                             float* __restrict__ attn_out) {
  int c = threadIdx.x;
  int h = __builtin_amdgcn_readfirstlane(threadIdx.x) >> 6;  // wave-uniform
  int r0 = blockIdx.x * TM;
  float acc[TM];
  #pragma unroll
  for (int r = 0; r < TM; r++) acc[r] = 0.f;
  #pragma unroll 4
  for (int ci = 0; ci < C_; ci++) {
    float w = Wv[ci * C_ + c];
    #pragma unroll
    for (int r = 0; r < TM; r++)
      acc[r] = fmaf(mix[((size_t)(r0 + r) * 6 + h) * C_ + ci], w, acc[r]);
  }
  #pragma unroll
  for (int r = 0; r < TM; r++) attn_out[(size_t)(r0 + r) * C_ + c] = acc[r];
}

// ---------------------------------------------------------------------------
extern "C" void kernel_launch(void* const* d_in, const int* in_sizes, int n_in,
                              void* d_out, int out_size, void* d_ws, size_t ws_size,
                              hipStream_t stream) {
  const float* q     = (const float*)d_in[0];
  const float* q_pos = (const float*)d_in[1];
  const float* Wq    = (const float*)d_in[2];
  const float* Wk    = (const float*)d_in[3];
  const float* Wv    = (const float*)d_in[4];
  const float* Wvoff = (const float*)d_in[5];
  const float* W1    = (const float*)d_in[6];
  const float* b1    = (const float*)d_in[7];
  const float* ln_g  = (const float*)d_in[8];
  const float* ln_b  = (const float*)d_in[9];
  const float* W2    = (const float*)d_in[10];
  const float* Wproj = (const float*)d_in[11];
  const float* bproj = (const float*)d_in[12];
  float* out = (float*)d_out;

  char* ws = (char*)d_ws;
  double* s64     = (double*)ws; ws += (size_t)B_ * N_ * 8;               // 32 KB
  int*    idx10   = (int*)ws;    ws += (size_t)B_ * N_ * K_ * 4;          // 160 KB
  float*  qp32    = (float*)ws;  ws += (size_t)B_ * N_ * C_ * 4;          // 6.3 MB
  double* M1      = (double*)ws; ws += (size_t)G_ * C_ * C_ * 8;          // 2.4 MB
  double* M2      = (double*)ws; ws += (size_t)G_ * C_ * C_ * 8;          // 2.4 MB
  double* Y1      = (double*)ws; ws += (size_t)B_ * N_ * G_ * C_ * 8;     // 25.2 MB
  double* Y2      = (double*)ws; ws += (size_t)B_ * N_ * G_ * C_ * 8;     // 25.2 MB
  double* shift64 = (double*)ws; ws += (size_t)M2_ * 3 * 8;               // 2 MB
  float*  interp  = (float*)ws;  ws += (size_t)B_ * N_ * K_ * C_ * 4;     // 63 MB
  float*  WkT     = (float*)ws;  ws += (size_t)C_ * C_ * 4;               // 0.6 MB
  float*  attn_out= (float*)ws;  ws += (size_t)B_ * N_ * C_ * 4;          // 6.3 MB
  // U/mix (37.75 MB) aliases the dead Y1+Y2 region (50.3 MB) after k_mlp64.
  float*  Umix    = (float*)Y1;

  k_sqnorm64<<<(B_ * N_ + 255) / 256, 256, 0, stream>>>(q_pos, s64);
  k_knn10_w<<<B_ * N_ / 4, 256, 0, stream>>>(q_pos, s64, idx10);
  k_gemmSA<16><<<B_ * N_ / 16, 384, 0, stream>>>(q, Wq, nullptr, qp32, B_ * N_);
  k_prepM<<<G_ * C_, 384, 0, stream>>>(Wvoff, Wq, W1, M1, M2);
  k_Y<16><<<dim3(B_ * N_ / 16, G_), 384, 0, stream>>>(q, M1, M2, Y1, Y2);
  k_mlp64<<<M2_ / 4, 256, 0, stream>>>(Y1, Y2, idx10, q_pos, b1, ln_g, ln_b, W2,
                                       shift64);
  k_interp64<<<M2_ / 4, 256, 0, stream>>>(shift64, q_pos, s64, q, interp);
  k_T<<<(C_ * C_ + 255) / 256, 256, 0, stream>>>(Wk, WkT);
  k_U<8><<<B_ * N_ / 8, 384, 0, stream>>>(qp32, WkT, Umix);
  k_attn2<<<B_ * N_ * 6 / 4, 256, 0, stream>>>(interp, Umix);
  k_out<16><<<B_ * N_ / 16, 384, 0, stream>>>(Umix, Wv, attn_out);
  k_gemmSA<16><<<B_ * N_ / 16, 384, 0, stream>>>(attn_out, Wproj, bproj, out, B_ * N_);
}

// Round 6
// 876.931 us; speedup vs baseline: 1.8976x; 1.0672x over previous
//
#include <hip/hip_runtime.h>
#include <math.h>

// Problem constants
constexpr int B_ = 4;
constexpr int N_ = 1024;
constexpr int C_ = 384;
constexpr int G_ = 2;
constexpr int K_ = 10;
constexpr int GD_ = 192;   // C_/G_
constexpr int NK_ = N_ * K_;           // 10240
constexpr int M2_ = B_ * G_ * N_ * K_; // 81920
constexpr float SCALE_ = 0.125f;       // 64^-0.5

// lexicographic (d, idx) compare == lax.top_k(-d) tie-break (lower idx wins)
__device__ __forceinline__ bool lless(double da, int ia, double db, int ib) {
  return (da < db) || (da == db && ia < ib);
}
__device__ __forceinline__ void lmin2(double& rd, int& ri, double ad, int ai,
                                      double bd, int bi) {
  bool t = lless(bd, bi, ad, ai);
  rd = t ? bd : ad; ri = t ? bi : ai;
}
__device__ __forceinline__ void lmax2(double& rd, int& ri, double ad, int ai,
                                      double bd, int bi) {
  bool t = lless(ad, ai, bd, bi);
  rd = t ? bd : ad; ri = t ? bi : ai;
}

// ---------------------------------------------------------------------------
// 1. fp64 squared norms of q_pos rows
__global__ void k_sqnorm64(const float* __restrict__ q_pos, double* __restrict__ s) {
  int i = blockIdx.x * blockDim.x + threadIdx.x;
  if (i >= B_ * N_) return;
  double x = q_pos[3 * i], y = q_pos[3 * i + 1], z = q_pos[3 * i + 2];
  s[i] = x * x + y * y + z * z;
}

// ---------------------------------------------------------------------------
// 2. KNN-10, wave-parallel: one 64-lane wave per query. Per-lane sorted top-10
//    over 16 strided candidates (branchless insertion network, fully unrolled),
//    then 6-step butterfly merge: C[r] = min(A[r],B[r], min_j max(A[j-1],B[r-j]))
__global__ __launch_bounds__(256) void k_knn10_w(const float* __restrict__ q_pos,
                                                 const double* __restrict__ s,
                                                 int* __restrict__ idx10) {
  int wid = (blockIdx.x * blockDim.x + threadIdx.x) >> 6;
  int lane = threadIdx.x & 63;
  if (wid >= B_ * N_) return;
  int b = wid / N_;
  double px = q_pos[3 * wid], py = q_pos[3 * wid + 1], pz = q_pos[3 * wid + 2];
  double sm = s[wid];
  const float* bp = q_pos + b * N_ * 3;
  const double* bs = s + b * N_;
  double d[K_]; int ix[K_];
  #pragma unroll
  for (int j = 0; j < K_; j++) { d[j] = INFINITY; ix[j] = 0x7fffffff; }
  for (int n0 = 0; n0 < N_; n0 += 64) {
    int n = n0 + lane;
    double dot = px * (double)bp[3 * n] + py * (double)bp[3 * n + 1] +
                 pz * (double)bp[3 * n + 2];
    double v = (sm - 2.0 * dot) + bs[n];
    bool c[K_];
    #pragma unroll
    for (int j = 0; j < K_; j++) c[j] = lless(v, n, d[j], ix[j]);
    #pragma unroll
    for (int j = K_ - 1; j >= 1; j--) {
      d[j]  = c[j] ? (c[j - 1] ? d[j - 1] : v) : d[j];
      ix[j] = c[j] ? (c[j - 1] ? ix[j - 1] : n) : ix[j];
    }
    d[0]  = c[0] ? v : d[0];
    ix[0] = c[0] ? n : ix[0];
  }
  #pragma unroll
  for (int off = 1; off < 64; off <<= 1) {
    double bd[K_]; int bi[K_];
    #pragma unroll
    for (int j = 0; j < K_; j++) {
      bd[j] = __shfl_xor(d[j], off);
      bi[j] = __shfl_xor(ix[j], off);
    }
    double md[K_]; int mi[K_];
    #pragma unroll
    for (int r = 0; r < K_; r++) {
      double m; int mj;
      lmin2(m, mj, d[r], ix[r], bd[r], bi[r]);
      #pragma unroll
      for (int j = 1; j <= r; j++) {
        double t; int ti;
        lmax2(t, ti, d[j - 1], ix[j - 1], bd[r - j], bi[r - j]);
        lmin2(m, mj, m, mj, t, ti);
      }
      md[r] = m; mi[r] = mj;
    }
    #pragma unroll
    for (int j = 0; j < K_; j++) { d[j] = md[j]; ix[j] = mi[j]; }
  }
  if (lane == 0) {
    #pragma unroll
    for (int j = 0; j < K_; j++) idx10[wid * K_ + j] = ix[j];
  }
}

// ---------------------------------------------------------------------------
// 3. fp32 GEMM, scalar-A: out[M x 384] = A @ W (+bias). Thread-per-column,
//    TM rows/block; A read via uniform addresses -> s_load, no LDS.
template <int TM>
__global__ __launch_bounds__(384) void k_gemmSA(const float* __restrict__ A,
                                                const float* __restrict__ W,
                                                const float* __restrict__ bias,
                                                float* __restrict__ out, int M) {
  int c = threadIdx.x;
  int r0 = blockIdx.x * TM;
  float acc[TM];
  #pragma unroll
  for (int r = 0; r < TM; r++) acc[r] = 0.f;
  #pragma unroll 4
  for (int j = 0; j < C_; j++) {
    float w = W[j * C_ + c];
    #pragma unroll
    for (int r = 0; r < TM; r++) acc[r] = fmaf(A[(r0 + r) * C_ + j], w, acc[r]);
  }
  float bv = bias ? bias[c] : 0.f;
  #pragma unroll
  for (int r = 0; r < TM; r++) out[(r0 + r) * C_ + c] = acc[r] + bv;
}

// ---------------------------------------------------------------------------
// 4. Fused weight products (fp64):
//    M1[g][k][c] = sum_d Wvoff[k][g*GD+d] * W1[d][c]
//    M2[g][k][c] = sum_d Wq  [k][g*GD+d] * W1[GD+d][c]
__global__ __launch_bounds__(384) void k_prepM(const float* __restrict__ Wvoff,
                                               const float* __restrict__ Wq,
                                               const float* __restrict__ W1,
                                               double* __restrict__ M1,
                                               double* __restrict__ M2) {
  int g = blockIdx.x / C_;
  int k = blockIdx.x % C_;
  int c = threadIdx.x;
  const float* wv = Wvoff + k * C_ + g * GD_;
  const float* wq = Wq + k * C_ + g * GD_;
  double a1 = 0.0, a2 = 0.0;
  for (int d = 0; d < GD_; d++) {
    a1 += (double)wv[d] * (double)W1[d * C_ + c];
    a2 += (double)wq[d] * (double)W1[(GD_ + d) * C_ + c];
  }
  M1[(g * C_ + k) * C_ + c] = a1;
  M2[(g * C_ + k) * C_ + c] = a2;
}

// ---------------------------------------------------------------------------
// 5. Y1 = q @ M1[g], Y2 = q @ M2[g]  (fp64 accumulate; scalar-A, no LDS)
//    TM=8 -> 1024 workgroups -> 24 waves/CU (was 12 at TM=16, occupancy-capped)
template <int TM>
__global__ __launch_bounds__(384) void k_Y(const float* __restrict__ q,
                                           const double* __restrict__ M1,
                                           const double* __restrict__ M2,
                                           double* __restrict__ Y1,
                                           double* __restrict__ Y2) {
  int c = threadIdx.x;
  int g = blockIdx.y;
  int r0 = blockIdx.x * TM;
  double a1[TM], a2[TM];
  #pragma unroll
  for (int r = 0; r < TM; r++) { a1[r] = 0.0; a2[r] = 0.0; }
  const double* m1 = M1 + (size_t)(g * C_) * C_ + c;
  const double* m2 = M2 + (size_t)(g * C_) * C_ + c;
  for (int k = 0; k < C_; k++) {
    double v1 = m1[(size_t)k * C_];
    double v2 = m2[(size_t)k * C_];
    #pragma unroll
    for (int r = 0; r < TM; r++) {
      double av = (double)q[(r0 + r) * C_ + k];
      a1[r] += av * v1;
      a2[r] += av * v2;
    }
  }
  #pragma unroll
  for (int r = 0; r < TM; r++) {
    Y1[((size_t)(r0 + r) * G_ + g) * C_ + c] = a1[r];
    Y2[((size_t)(r0 + r) * G_ + g) * C_ + c] = a2[r];
  }
}

// ---------------------------------------------------------------------------
// 6. Per-row fp64: h = Y1[gathered] + Y2 + b1 -> LN -> gelu -> @W2 -> tanh
//    -> shift64 = q_pos[gathered] + offset.  One wave per row.
__global__ __launch_bounds__(256) void k_mlp64(const double* __restrict__ Y1,
                                               const double* __restrict__ Y2,
                                               const int* __restrict__ idx10,
                                               const float* __restrict__ q_pos,
                                               const float* __restrict__ b1,
                                               const float* __restrict__ ln_g,
                                               const float* __restrict__ ln_b,
                                               const float* __restrict__ W2,
                                               double* __restrict__ shift64) {
  int w_ = threadIdx.x >> 6, l = threadIdx.x & 63;
  int row = blockIdx.x * 4 + w_;
  int k = row % K_; int t = row / K_;
  int n = t % N_; t /= N_;
  int g = t % G_; int b = t / G_;
  int j = idx10[(b * N_ + n) * K_ + k];
  const double* y1 = Y1 + ((size_t)(b * N_ + j) * G_ + g) * C_;
  const double* y2 = Y2 + ((size_t)(b * N_ + n) * G_ + g) * C_;
  double x[6];
  #pragma unroll
  for (int jj = 0; jj < 6; jj++) {
    int col = l + 64 * jj;
    x[jj] = y1[col] + y2[col] + (double)b1[col];
  }
  double sum = ((((x[0] + x[1]) + x[2]) + x[3]) + x[4]) + x[5];
  #pragma unroll
  for (int off = 1; off < 64; off <<= 1) sum += __shfl_xor(sum, off);
  double mu = sum / 384.0;
  double sq = 0.0;
  #pragma unroll
  for (int jj = 0; jj < 6; jj++) { double dd = x[jj] - mu; sq += dd * dd; }
  #pragma unroll
  for (int off = 1; off < 64; off <<= 1) sq += __shfl_xor(sq, off);
  double var = sq / 384.0;
  double rstd = 1.0 / sqrt(var + 1e-5);
  double ge[6];
  #pragma unroll
  for (int jj = 0; jj < 6; jj++) {
    int col = l + 64 * jj;
    double nv = (x[jj] - mu) * rstd * (double)ln_g[col] + (double)ln_b[col];
    ge[jj] = 0.5 * nv * (1.0 + erf(nv * 0.70710678118654752440));
  }
  double o3[3];
  #pragma unroll
  for (int o = 0; o < 3; o++) {
    double p = 0.0;
    #pragma unroll
    for (int jj = 0; jj < 6; jj++) {
      int col = l + 64 * jj;
      p += ge[jj] * (double)W2[col * 3 + o];
    }
    #pragma unroll
    for (int off = 1; off < 64; off <<= 1) p += __shfl_xor(p, off);
    o3[o] = tanh(p);
  }
  if (l == 0) {
    int gi = b * N_ + j;
    shift64[(size_t)row * 3 + 0] = (double)q_pos[gi * 3 + 0] + o3[0];
    shift64[(size_t)row * 3 + 1] = (double)q_pos[gi * 3 + 1] + o3[1];
    shift64[(size_t)row * 3 + 2] = (double)q_pos[gi * 3 + 2] + o3[2];
  }
}

// ---------------------------------------------------------------------------
// 7. fp64 top-3 selection + fp32 inverse-distance interp (interp feeds only
//    the continuous fp32 attention path). One wave per (b,g,m).
__global__ __launch_bounds__(256) void k_interp64(const double* __restrict__ shift64,
                                                  const float* __restrict__ q_pos,
                                                  const double* __restrict__ s64,
                                                  const float* __restrict__ q,
                                                  float* __restrict__ interp) {
  int wid = (blockIdx.x * blockDim.x + threadIdx.x) >> 6;
  int lane = threadIdx.x & 63;
  int m = wid % NK_; int t = wid / NK_;
  int g = t % G_; int b = t / G_;
  double px = shift64[(size_t)wid * 3], py = shift64[(size_t)wid * 3 + 1],
         pz = shift64[(size_t)wid * 3 + 2];
  double sp = px * px + py * py + pz * pz;
  const float* bp = q_pos + b * N_ * 3;
  const double* bs = s64 + b * N_;
  double d0 = INFINITY, d1 = INFINITY, d2 = INFINITY;
  int i0 = 0x7fffffff, i1 = 0x7fffffff, i2 = 0x7fffffff;
  for (int n = lane; n < N_; n += 64) {
    double dot = px * (double)bp[3 * n] + py * (double)bp[3 * n + 1] +
                 pz * (double)bp[3 * n + 2];
    double dd = (sp - 2.0 * dot) + bs[n];
    bool c0 = lless(dd, n, d0, i0);
    bool c1 = lless(dd, n, d1, i1);
    bool c2 = lless(dd, n, d2, i2);
    double nd2 = c2 ? (c1 ? d1 : dd) : d2; int ni2 = c2 ? (c1 ? i1 : n) : i2;
    double nd1 = c1 ? (c0 ? d0 : dd) : d1; int ni1 = c1 ? (c0 ? i0 : n) : i1;
    double nd0 = c0 ? dd : d0;             int ni0 = c0 ? n : i0;
    d0 = nd0; d1 = nd1; d2 = nd2; i0 = ni0; i1 = ni1; i2 = ni2;
  }
  #pragma unroll
  for (int off = 1; off < 64; off <<= 1) {
    double e0 = __shfl_xor(d0, off), e1 = __shfl_xor(d1, off), e2 = __shfl_xor(d2, off);
    int j0 = __shfl_xor(i0, off), j1 = __shfl_xor(i1, off), j2 = __shfl_xor(i2, off);
    double mnd, mxd, p1d, q1d, q2d, q3d, q4d, t1d, t2d;
    int mni, mxi, p1i, q1i, q2i, q3i, q4i, t1i, t2i;
    lmin2(mnd, mni, d0, i0, e0, j0);
    lmax2(mxd, mxi, d0, i0, e0, j0);
    lmin2(p1d, p1i, d1, i1, e1, j1);
    lmin2(t1d, t1i, p1d, p1i, mxd, mxi);
    lmax2(q1d, q1i, d1, i1, e0, j0);
    lmax2(q2d, q2i, d0, i0, e1, j1);
    lmin2(q3d, q3i, q1d, q1i, q2d, q2i);
    lmin2(q4d, q4i, d2, i2, e2, j2);
    lmin2(t2d, t2i, q3d, q3i, q4d, q4i);
    d0 = mnd; i0 = mni; d1 = t1d; i1 = t1i; d2 = t2d; i2 = t2i;
  }
  double r0 = 1.0 / (d0 + 1e-8);
  double r1 = 1.0 / (d1 + 1e-8);
  double r2 = 1.0 / (d2 + 1e-8);
  double rs = (r0 + r1) + r2;
  float w0 = (float)(r0 / rs), w1 = (float)(r1 / rs), w2 = (float)(r2 / rs);
  const float* qb = q + (size_t)b * N_ * C_ + g * GD_;
  const float* p0 = qb + (size_t)i0 * C_;
  const float* p1 = qb + (size_t)i1 * C_;
  const float* p2 = qb + (size_t)i2 * C_;
  int n_ = m / K_, k_ = m % K_;
  float* op = interp + (((size_t)(b * N_ + n_) * K_ + k_) * C_) + g * GD_;
  for (int cc = lane; cc < GD_; cc += 64) {
    op[cc] = (w0 * p0[cc] + w1 * p1[cc]) + w2 * p2[cc];
  }
}

// ---------------------------------------------------------------------------
// 8a. Transpose Wk -> WkT (WkT[col][row] = Wk[row][col])
__global__ __launch_bounds__(256) void k_T(const float* __restrict__ Wk,
                                           float* __restrict__ WkT) {
  int i = blockIdx.x * blockDim.x + threadIdx.x;
  if (i >= C_ * C_) return;
  int r = i / C_, c = i % C_;
  WkT[c * C_ + r] = Wk[i];
}

// ---------------------------------------------------------------------------
// 8b. U[bn][h][c] = sum_d qp[bn, h*64+d] * Wk[c, h*64+d]  (via WkT, scalar-A qp)
template <int TM>
__global__ __launch_bounds__(384) void k_U(const float* __restrict__ qp,
                                           const float* __restrict__ WkT,
                                           float* __restrict__ U) {
  int c = threadIdx.x;
  int r0 = blockIdx.x * TM;
  for (int h = 0; h < 6; h++) {
    float acc[TM];
    #pragma unroll
    for (int r = 0; r < TM; r++) acc[r] = 0.f;
    #pragma unroll 4
    for (int dd = 0; dd < 64; dd++) {
      float w = WkT[(h * 64 + dd) * C_ + c];
      #pragma unroll
      for (int r = 0; r < TM; r++)
        acc[r] = fmaf(qp[(r0 + r) * C_ + h * 64 + dd], w, acc[r]);
    }
    #pragma unroll
    for (int r = 0; r < TM; r++) U[((size_t)(r0 + r) * 6 + h) * C_ + c] = acc[r];
  }
}

// ---------------------------------------------------------------------------
// 8c. Per (bn, h) wave: logits = interp·U, softmax, mix = attn·interp.
//     Writes mix IN PLACE over U (same row, read fully before write).
__global__ __launch_bounds__(256) void k_attn2(const float* __restrict__ interp,
                                               float* __restrict__ Umix) {
  int wid = blockIdx.x * 4 + (threadIdx.x >> 6);
  int lane = threadIdx.x & 63;
  int h = wid % 6, bn = wid / 6;
  float* urow = Umix + (size_t)wid * C_;
  float u[6];
  #pragma unroll
  for (int j = 0; j < 6; j++) u[j] = urow[lane + 64 * j];
  float logit[K_];
  #pragma unroll
  for (int k = 0; k < K_; k++) {
    const float* ip = interp + ((size_t)bn * K_ + k) * C_;
    float p = 0.f;
    #pragma unroll
    for (int j = 0; j < 6; j++) p = fmaf(ip[lane + 64 * j], u[j], p);
    #pragma unroll
    for (int off = 1; off < 64; off <<= 1) p += __shfl_xor(p, off);
    logit[k] = p * SCALE_;
  }
  float mx = logit[0];
  #pragma unroll
  for (int k = 1; k < K_; k++) mx = fmaxf(mx, logit[k]);
  float e[K_], se = 0.f;
  #pragma unroll
  for (int k = 0; k < K_; k++) { e[k] = expf(logit[k] - mx); se += e[k]; }
  float inv = 1.0f / se;
  #pragma unroll
  for (int k = 0; k < K_; k++) e[k] *= inv;
  #pragma unroll
  for (int j = 0; j < 6; j++) {
    float mv = 0.f;
    #pragma unroll
    for (int k = 0; k < K_; k++)
      mv = fmaf(e[k], interp[((size_t)bn * K_ + k) * C_ + lane + 64 * j], mv);
    urow[lane + 64 * j] = mv;
  }
  (void)h;
}

// ---------------------------------------------------------------------------
// 8d. attn_out[bn, c] = mix[bn, c/64, :] @ Wv[:, c]  (scalar-A mix via
//     readfirstlane'd head index -> s_load)
template <int TM>
__global__ __launch_bounds__(384) void k_out(const float* __restrict__ mix,
                                             const float* __restrict__ Wv,
                                             float* __restrict__ attn_out) {
  int c = threadIdx.x;
  int h = __builtin_amdgcn_readfirstlane(threadIdx.x) >> 6;  // wave-uniform
  int r0 = blockIdx.x * TM;
  float acc[TM];
  #pragma unroll
  for (int r = 0; r < TM; r++) acc[r] = 0.f;
  #pragma unroll 4
  for (int ci = 0; ci < C_; ci++) {
    float w = Wv[ci * C_ + c];
    #pragma unroll
    for (int r = 0; r < TM; r++)
      acc[r] = fmaf(mix[((size_t)(r0 + r) * 6 + h) * C_ + ci], w, acc[r]);
  }
  #pragma unroll
  for (int r = 0; r < TM; r++) attn_out[(size_t)(r0 + r) * C_ + c] = acc[r];
}

// ---------------------------------------------------------------------------
extern "C" void kernel_launch(void* const* d_in, const int* in_sizes, int n_in,
                              void* d_out, int out_size, void* d_ws, size_t ws_size,
                              hipStream_t stream) {
  const float* q     = (const float*)d_in[0];
  const float* q_pos = (const float*)d_in[1];
  const float* Wq    = (const float*)d_in[2];
  const float* Wk    = (const float*)d_in[3];
  const float* Wv    = (const float*)d_in[4];
  const float* Wvoff = (const float*)d_in[5];
  const float* W1    = (const float*)d_in[6];
  const float* b1    = (const float*)d_in[7];
  const float* ln_g  = (const float*)d_in[8];
  const float* ln_b  = (const float*)d_in[9];
  const float* W2    = (const float*)d_in[10];
  const float* Wproj = (const float*)d_in[11];
  const float* bproj = (const float*)d_in[12];
  float* out = (float*)d_out;

  char* ws = (char*)d_ws;
  double* s64     = (double*)ws; ws += (size_t)B_ * N_ * 8;               // 32 KB
  int*    idx10   = (int*)ws;    ws += (size_t)B_ * N_ * K_ * 4;          // 160 KB
  float*  qp32    = (float*)ws;  ws += (size_t)B_ * N_ * C_ * 4;          // 6.3 MB
  double* M1      = (double*)ws; ws += (size_t)G_ * C_ * C_ * 8;          // 2.4 MB
  double* M2      = (double*)ws; ws += (size_t)G_ * C_ * C_ * 8;          // 2.4 MB
  double* Y1      = (double*)ws; ws += (size_t)B_ * N_ * G_ * C_ * 8;     // 25.2 MB
  double* Y2      = (double*)ws; ws += (size_t)B_ * N_ * G_ * C_ * 8;     // 25.2 MB
  double* shift64 = (double*)ws; ws += (size_t)M2_ * 3 * 8;               // 2 MB
  float*  interp  = (float*)ws;  ws += (size_t)B_ * N_ * K_ * C_ * 4;     // 63 MB
  float*  WkT     = (float*)ws;  ws += (size_t)C_ * C_ * 4;               // 0.6 MB
  float*  attn_out= (float*)ws;  ws += (size_t)B_ * N_ * C_ * 4;          // 6.3 MB
  // U/mix (37.75 MB) aliases the dead Y1+Y2 region (50.3 MB) after k_mlp64.
  float*  Umix    = (float*)Y1;

  k_sqnorm64<<<(B_ * N_ + 255) / 256, 256, 0, stream>>>(q_pos, s64);
  k_knn10_w<<<B_ * N_ / 4, 256, 0, stream>>>(q_pos, s64, idx10);
  k_gemmSA<16><<<B_ * N_ / 16, 384, 0, stream>>>(q, Wq, nullptr, qp32, B_ * N_);
  k_prepM<<<G_ * C_, 384, 0, stream>>>(Wvoff, Wq, W1, M1, M2);
  k_Y<8><<<dim3(B_ * N_ / 8, G_), 384, 0, stream>>>(q, M1, M2, Y1, Y2);
  k_mlp64<<<M2_ / 4, 256, 0, stream>>>(Y1, Y2, idx10, q_pos, b1, ln_g, ln_b, W2,
                                       shift64);
  k_interp64<<<M2_ / 4, 256, 0, stream>>>(shift64, q_pos, s64, q, interp);
  k_T<<<(C_ * C_ + 255) / 256, 256, 0, stream>>>(Wk, WkT);
  k_U<8><<<B_ * N_ / 8, 384, 0, stream>>>(qp32, WkT, Umix);
  k_attn2<<<B_ * N_ * 6 / 4, 256, 0, stream>>>(interp, Umix);
  k_out<16><<<B_ * N_ / 16, 384, 0, stream>>>(Umix, Wv, attn_out);
  k_gemmSA<16><<<B_ * N_ / 16, 384, 0, stream>>>(attn_out, Wproj, bproj, out, B_ * N_);
}